// Round 7
// baseline (1521.783 us; speedup 1.0000x reference)
//
#include <hip/hip_runtime.h>
#include <math.h>

#define N_NODES 150000
#define HALFN 75000          // node-pair split for fused_agg ILP
#define NODE_STRIDE 150016   // padded per-step stride for meta array
#define DIM 100
#define D4 25                // DIM/4 float4 chunks
#define T_STEPS 16
#define E_EDGES 262144
#define S_SEEDS 4096
#define K_CAND 9
#define SPB 16               // seeds per LSTM block

#define CB 64                // coarse buckets per step
#define BSPAN 2344           // nodes per coarse bucket; 64*2344 = 150016 >= N
#define EPT 8                // edges per thread in coarse passes
#define EPB (256 * EPT)      // 2048 edges per coarse block
#define CBLK (E_EDGES / EPB) // 128 coarse blocks per step

__device__ __forceinline__ float sigmoidf_(float x) {
    return 1.0f / (1.0f + __expf(-x));
}

// ============ CSR build: atomic-free two-level counting sort ============

__global__ __launch_bounds__(256) void coarse_hist(
    const int* __restrict__ dst, int* __restrict__ bh) {
    int t = blockIdx.x / CBLK;
    int blk = blockIdx.x % CBLK;
    int base = t * E_EDGES + blk * EPB;
    int tid = threadIdx.x;
    __shared__ int h[CB];
    if (tid < CB) h[tid] = 0;
    __syncthreads();
#pragma unroll
    for (int e = 0; e < EPT; e++) {
        int d = dst[base + e * 256 + tid];
        atomicAdd(&h[d / BSPAN], 1);
    }
    __syncthreads();
    if (tid < CB) bh[(t * CBLK + blk) * CB + tid] = h[tid];
}

__global__ __launch_bounds__(64) void scan_bh(
    int* __restrict__ bh, int* __restrict__ coffs) {
    int t = blockIdx.x;
    int b = threadIdx.x;          // 64 threads = 64 buckets
    int run = 0;
    for (int blk = 0; blk < CBLK; blk++) {
        int idx = (t * CBLK + blk) * CB + b;
        int v = bh[idx];
        bh[idx] = run;
        run += v;
    }
    __shared__ int tot[CB];
    tot[b] = run;
    __syncthreads();
    if (b == 0) {
        int r = 0;
        for (int i = 0; i < CB; i++) { int c = tot[i]; tot[i] = r; r += c; }
    }
    __syncthreads();
    coffs[t * (CB + 1) + b] = tot[b];
    if (b == 0) coffs[t * (CB + 1) + CB] = E_EDGES;
}

__global__ __launch_bounds__(256) void coarse_scatter(
    const int* __restrict__ src, const int* __restrict__ dst,
    const int* __restrict__ cat, const int* __restrict__ bh,
    const int* __restrict__ coffs, int2* __restrict__ cbuf) {
    int t = blockIdx.x / CBLK;
    int blk = blockIdx.x % CBLK;
    int base = t * E_EDGES + blk * EPB;
    int tid = threadIdx.x;
    __shared__ int h[CB];
    __shared__ int gbase[CB];
    if (tid < CB) h[tid] = 0;
    __syncthreads();
    int rank[EPT], bb[EPT], dd[EPT];
#pragma unroll
    for (int e = 0; e < EPT; e++) {
        int d = dst[base + e * 256 + tid];
        int b = d / BSPAN;
        dd[e] = d; bb[e] = b;
        rank[e] = atomicAdd(&h[b], 1);
    }
    __syncthreads();
    if (tid < CB)
        gbase[tid] = coffs[t * (CB + 1) + tid] + bh[(t * CBLK + blk) * CB + tid];
    __syncthreads();
#pragma unroll
    for (int e = 0; e < EPT; e++) {
        int i = base + e * 256 + tid;
        int2 en;
        en.x = src[i] | (cat[i] << 18);
        en.y = dd[e];
        cbuf[(size_t)t * E_EDGES + gbase[bb[e]] + rank[e]] = en;
    }
}

__global__ __launch_bounds__(256) void fine_build(
    const int2* __restrict__ cbuf, const int* __restrict__ coffs,
    int4* __restrict__ meta, int* __restrict__ sorted) {
    int t = blockIdx.x >> 6;
    int b = blockIdx.x & 63;
    int node0 = b * BSPAN;
    int nodes = min(BSPAN, N_NODES - node0);
    int ebeg = coffs[t * (CB + 1) + b];
    int eend = coffs[t * (CB + 1) + b + 1];
    const int2* ebuf = cbuf + (size_t)t * E_EDGES;
    int4* mt = meta + (size_t)t * NODE_STRIDE;
    int* srt = sorted + (size_t)t * E_EDGES;
    __shared__ int cnt[BSPAN];     // counts -> cursor
    __shared__ int begs[BSPAN];    // local exclusive offsets
    __shared__ int sums[256];
    int tid = threadIdx.x;

    for (int j = tid; j < BSPAN; j += 256) cnt[j] = 0;
    __syncthreads();
    for (int e = ebeg + tid; e < eend; e += 256)
        atomicAdd(&cnt[ebuf[e].y - node0], 1);
    __syncthreads();

    const int chunk = (BSPAN + 255) / 256;   // 10
    int cbeg = tid * chunk;
    int cend = min(cbeg + chunk, BSPAN);
    int s = 0;
    for (int j = cbeg; j < cend; j++) s += cnt[j];
    sums[tid] = s;
    __syncthreads();
    for (int d = 1; d < 256; d <<= 1) {
        int v = (tid >= d) ? sums[tid - d] : 0;
        __syncthreads();
        sums[tid] += v;
        __syncthreads();
    }
    int run = (tid == 0) ? 0 : sums[tid - 1];
    for (int j = cbeg; j < cend; j++) {
        int c = cnt[j];
        begs[j] = run;
        cnt[j] = run;                // cursor
        run += c;
    }
    __syncthreads();

    for (int e = ebeg + tid; e < eend; e += 256) {
        int2 en = ebuf[e];
        int pos = atomicAdd(&cnt[en.y - node0], 1);
        srt[ebeg + pos] = en.x;
    }
    __syncthreads();

    for (int j = tid; j < nodes; j += 256) {
        int lbeg = begs[j];
        int deg = cnt[j] - lbeg;
        int gbeg = ebeg + lbeg;
        int4 m;
        m.x = gbeg | (deg << 19);    // gbeg <= 2^18, deg < 2^13
        m.y = (deg > 0) ? srt[gbeg] : 0;
        m.z = (deg > 1) ? srt[gbeg + 1] : 0;
        m.w = (deg > 2) ? srt[gbeg + 2] : 0;
        mt[node0 + j] = m;
    }
}

// ============ Per-step fused aggregation + residual (gather, no atomics) ====
// Node-PAIR per thread (n, n+75000) with branchless deg<=3 fast path:
// all gather loads issue unconditionally (masked-zero accumulate; fallback
// address = own row -> L1 hit). Doubles memory-level parallelism per thread.
// FP order per node unchanged (adding exact 0.0 terms preserves values).
__global__ __launch_bounds__(256) void fused_agg(
    const float* __restrict__ emb_in, float* __restrict__ emb_out,
    const float* __restrict__ rel_emb, const int4* __restrict__ meta,
    const int* __restrict__ sorted) {
    unsigned idx = blockIdx.x * 256u + threadIdx.x;
    unsigned pr = idx / 25u;             // pair index
    unsigned q = idx - pr * 25u;
    if (pr >= HALFN) return;
    unsigned n0 = pr, n1 = pr + HALFN;

    int4 m0 = meta[n0];
    int4 m1 = meta[n1];
    float4 own0 = ((const float4*)(emb_in + (size_t)n0 * DIM))[q];
    float4 own1 = ((const float4*)(emb_in + (size_t)n1 * DIM))[q];

    int deg0 = ((unsigned)m0.x) >> 19, beg0 = m0.x & 0x7FFFF;
    int deg1 = ((unsigned)m1.x) >> 19, beg1 = m1.x & 0x7FFFF;

    // branchless gather indices (fallback: own row / rel row 0)
    unsigned ga0 = (deg0 > 0) ? (unsigned)(m0.y & 0x3FFFF) : n0;
    unsigned gb0 = (deg0 > 1) ? (unsigned)(m0.z & 0x3FFFF) : n0;
    unsigned gc0 = (deg0 > 2) ? (unsigned)(m0.w & 0x3FFFF) : n0;
    unsigned ra0 = (deg0 > 0) ? ((unsigned)m0.y >> 18) : 0u;
    unsigned rb0 = (deg0 > 1) ? ((unsigned)m0.z >> 18) : 0u;
    unsigned rc0 = (deg0 > 2) ? ((unsigned)m0.w >> 18) : 0u;
    unsigned ga1 = (deg1 > 0) ? (unsigned)(m1.y & 0x3FFFF) : n1;
    unsigned gb1 = (deg1 > 1) ? (unsigned)(m1.z & 0x3FFFF) : n1;
    unsigned gc1 = (deg1 > 2) ? (unsigned)(m1.w & 0x3FFFF) : n1;
    unsigned ra1 = (deg1 > 0) ? ((unsigned)m1.y >> 18) : 0u;
    unsigned rb1 = (deg1 > 1) ? ((unsigned)m1.z >> 18) : 0u;
    unsigned rc1 = (deg1 > 2) ? ((unsigned)m1.w >> 18) : 0u;

    // issue all 12 gather loads unconditionally (max MLP)
    float4 A0 = ((const float4*)(emb_in + (size_t)ga0 * DIM))[q];
    float4 B0 = ((const float4*)(emb_in + (size_t)gb0 * DIM))[q];
    float4 C0 = ((const float4*)(emb_in + (size_t)gc0 * DIM))[q];
    float4 A1 = ((const float4*)(emb_in + (size_t)ga1 * DIM))[q];
    float4 B1 = ((const float4*)(emb_in + (size_t)gb1 * DIM))[q];
    float4 C1 = ((const float4*)(emb_in + (size_t)gc1 * DIM))[q];
    float4 Ra0 = ((const float4*)(rel_emb + (size_t)ra0 * DIM))[q];
    float4 Rb0 = ((const float4*)(rel_emb + (size_t)rb0 * DIM))[q];
    float4 Rc0 = ((const float4*)(rel_emb + (size_t)rc0 * DIM))[q];
    float4 Ra1 = ((const float4*)(rel_emb + (size_t)ra1 * DIM))[q];
    float4 Rb1 = ((const float4*)(rel_emb + (size_t)rb1 * DIM))[q];
    float4 Rc1 = ((const float4*)(rel_emb + (size_t)rc1 * DIM))[q];

    float wa0 = (deg0 > 0) ? 1.0f : 0.0f;
    float wb0 = (deg0 > 1) ? 1.0f : 0.0f;
    float wc0 = (deg0 > 2) ? 1.0f : 0.0f;
    float wa1 = (deg1 > 0) ? 1.0f : 0.0f;
    float wb1 = (deg1 > 1) ? 1.0f : 0.0f;
    float wc1 = (deg1 > 2) ? 1.0f : 0.0f;

    float4 acc0, acc1;
    acc0.x = A0.x * Ra0.x * wa0; acc0.y = A0.y * Ra0.y * wa0;
    acc0.z = A0.z * Ra0.z * wa0; acc0.w = A0.w * Ra0.w * wa0;
    acc0.x += B0.x * Rb0.x * wb0; acc0.y += B0.y * Rb0.y * wb0;
    acc0.z += B0.z * Rb0.z * wb0; acc0.w += B0.w * Rb0.w * wb0;
    acc0.x += C0.x * Rc0.x * wc0; acc0.y += C0.y * Rc0.y * wc0;
    acc0.z += C0.z * Rc0.z * wc0; acc0.w += C0.w * Rc0.w * wc0;
    acc1.x = A1.x * Ra1.x * wa1; acc1.y = A1.y * Ra1.y * wa1;
    acc1.z = A1.z * Ra1.z * wa1; acc1.w = A1.w * Ra1.w * wa1;
    acc1.x += B1.x * Rb1.x * wb1; acc1.y += B1.y * Rb1.y * wb1;
    acc1.z += B1.z * Rb1.z * wb1; acc1.w += B1.w * Rb1.w * wb1;
    acc1.x += C1.x * Rc1.x * wc1; acc1.y += C1.y * Rc1.y * wc1;
    acc1.z += C1.z * Rc1.z * wc1; acc1.w += C1.w * Rc1.w * wc1;

    // overflow path (deg > 3, rare): walk CSR slice
    for (int e = beg0 + 3; e < beg0 + deg0; e++) {
        int p = sorted[e];
        float4 mm = ((const float4*)(emb_in + (size_t)(p & 0x3FFFF) * DIM))[q];
        float4 rr = ((const float4*)(rel_emb + (size_t)(p >> 18) * DIM))[q];
        acc0.x += mm.x * rr.x; acc0.y += mm.y * rr.y;
        acc0.z += mm.z * rr.z; acc0.w += mm.w * rr.w;
    }
    for (int e = beg1 + 3; e < beg1 + deg1; e++) {
        int p = sorted[e];
        float4 mm = ((const float4*)(emb_in + (size_t)(p & 0x3FFFF) * DIM))[q];
        float4 rr = ((const float4*)(rel_emb + (size_t)(p >> 18) * DIM))[q];
        acc1.x += mm.x * rr.x; acc1.y += mm.y * rr.y;
        acc1.z += mm.z * rr.z; acc1.w += mm.w * rr.w;
    }

    float inv0 = (deg0 > 0) ? 1.0f / (float)deg0 : 0.0f;
    float inv1 = (deg1 > 0) ? 1.0f / (float)deg1 : 0.0f;
    own0.x += acc0.x * inv0; own0.y += acc0.y * inv0;
    own0.z += acc0.z * inv0; own0.w += acc0.w * inv0;
    own1.x += acc1.x * inv1; own1.y += acc1.y * inv1;
    own1.z += acc1.z * inv1; own1.w += acc1.w * inv1;
    ((float4*)(emb_out + (size_t)n0 * DIM))[q] = own0;
    ((float4*)(emb_out + (size_t)n1 * DIM))[q] = own1;
}

// ============ LSTM on seeds (x from emb_new, h_prev from emb_old) ===========
__global__ __launch_bounds__(512) void lstm_kernel(
    const float* __restrict__ emb_new, const float* __restrict__ emb_old,
    const float* __restrict__ c_state, const int* __restrict__ seeds,
    const float* __restrict__ W_ih, const float* __restrict__ W_hh,
    const float* __restrict__ b_ih, const float* __restrict__ b_hh,
    float* __restrict__ h_out, float* __restrict__ c_out) {
    __shared__ __align__(16) float xs[SPB][DIM];
    __shared__ __align__(16) float hs[SPB][DIM];
    __shared__ __align__(16) float gates[SPB][4 * DIM];
    int tid = threadIdx.x;
    int base = blockIdx.x * SPB;

    // float4-vectorized staging (identical values, wider loads)
    for (int idx = tid; idx < SPB * D4; idx += 512) {
        int s = idx / D4, q = idx - s * D4;
        int node = seeds[base + s];
        ((float4*)xs[s])[q] = ((const float4*)(emb_new + (size_t)node * DIM))[q];
        ((float4*)hs[s])[q] = ((const float4*)(emb_old + (size_t)node * DIM))[q];
    }
    __syncthreads();

    if (tid < 4 * DIM) {
        int j = tid;
        float acc[SPB];
#pragma unroll
        for (int s = 0; s < SPB; s++) acc[s] = 0.0f;
        const float4* wi = (const float4*)(W_ih + (size_t)j * DIM);
        const float4* wh = (const float4*)(W_hh + (size_t)j * DIM);
        for (int dc = 0; dc < D4; dc++) {
            float4 a = wi[dc], b = wh[dc];
#pragma unroll
            for (int s = 0; s < SPB; s++) {
                float4 x = ((const float4*)xs[s])[dc];
                float4 h = ((const float4*)hs[s])[dc];
                acc[s] += x.x * a.x + x.y * a.y + x.z * a.z + x.w * a.w
                        + h.x * b.x + h.y * b.y + h.z * b.z + h.w * b.w;
            }
        }
        float bb = b_ih[j] + b_hh[j];
#pragma unroll
        for (int s = 0; s < SPB; s++) gates[s][j] = acc[s] + bb;
    }
    __syncthreads();

    // float4-vectorized activation tail (same per-element math)
    for (int idx = tid; idx < SPB * D4; idx += 512) {
        int s = idx / D4, q = idx - s * D4;
        int node = seeds[base + s];
        float4 ig = ((const float4*)gates[s])[q];
        float4 fg = ((const float4*)(gates[s] + DIM))[q];
        float4 gg = ((const float4*)(gates[s] + 2 * DIM))[q];
        float4 og = ((const float4*)(gates[s] + 3 * DIM))[q];
        float4 cp = ((const float4*)(c_state + (size_t)node * DIM))[q];
        float4 cn, hn;
        cn.x = sigmoidf_(fg.x) * cp.x + sigmoidf_(ig.x) * tanhf(gg.x);
        cn.y = sigmoidf_(fg.y) * cp.y + sigmoidf_(ig.y) * tanhf(gg.y);
        cn.z = sigmoidf_(fg.z) * cp.z + sigmoidf_(ig.z) * tanhf(gg.z);
        cn.w = sigmoidf_(fg.w) * cp.w + sigmoidf_(ig.w) * tanhf(gg.w);
        hn.x = sigmoidf_(og.x) * tanhf(cn.x);
        hn.y = sigmoidf_(og.y) * tanhf(cn.y);
        hn.z = sigmoidf_(og.z) * tanhf(cn.z);
        hn.w = sigmoidf_(og.w) * tanhf(cn.w);
        ((float4*)(h_out + (size_t)(base + s) * DIM))[q] = hn;
        ((float4*)(c_out + (size_t)(base + s) * DIM))[q] = cn;
    }
}

// duplicate seeds write identical values -> benign
__global__ __launch_bounds__(256) void scatter_seed(
    float* __restrict__ emb, float* __restrict__ c_state,
    const int* __restrict__ seeds,
    const float* __restrict__ h_new, const float* __restrict__ c_new) {
    int i = blockIdx.x * blockDim.x + threadIdx.x;  // over S*D4
    int sd = i / D4, q = i - sd * D4;
    int node = seeds[sd];
    ((float4*)(emb + (size_t)node * DIM))[q] =
        ((const float4*)(h_new + (size_t)sd * DIM))[q];
    ((float4*)(c_state + (size_t)node * DIM))[q] =
        ((const float4*)(c_new + (size_t)sd * DIM))[q];
}

// ============ Scoring ============
// Single-touch streams (seedh, cand_idx, out) use nontemporal hints so the
// 60MB emb table stays L3-resident for the 590K random candidate gathers.
__global__ __launch_bounds__(64) void score_kernel(
    const float* __restrict__ seed_h, const float* __restrict__ emb,
    const int* __restrict__ cand_idx, float* __restrict__ out) {
    int n = blockIdx.x;
    int lane = threadIdx.x;
    bool hi = lane + 64 < DIM;
    float u0 = __builtin_nontemporal_load(&seed_h[(size_t)n * DIM + lane]);
    float u1 = hi ? __builtin_nontemporal_load(&seed_h[(size_t)n * DIM + lane + 64])
                  : 0.0f;
    int cd[K_CAND];
#pragma unroll
    for (int k = 0; k < K_CAND; k++)
        cd[k] = __builtin_nontemporal_load(&cand_idx[n * K_CAND + k]);
    float p[K_CAND];
#pragma unroll
    for (int k = 0; k < K_CAND; k++) {
        const float* ce = emb + (size_t)cd[k] * DIM;
        p[k] = u0 * ce[lane];
        if (hi) p[k] += u1 * ce[lane + 64];
    }
#pragma unroll
    for (int k = 0; k < K_CAND; k++) {
        for (int off = 32; off > 0; off >>= 1)
            p[k] += __shfl_down(p[k], off);
        if (lane == 0)
            __builtin_nontemporal_store(p[k], &out[n * K_CAND + k]);
    }
}

extern "C" void kernel_launch(void* const* d_in, const int* in_sizes, int n_in,
                              void* d_out, int out_size, void* d_ws, size_t ws_size,
                              hipStream_t stream) {
    const float* node_emb = (const float*)d_in[0];
    const float* cx       = (const float*)d_in[1];
    const float* rel_emb  = (const float*)d_in[2];
    const float* W_ih     = (const float*)d_in[3];
    const float* W_hh     = (const float*)d_in[4];
    const float* b_ih     = (const float*)d_in[5];
    const float* b_hh     = (const float*)d_in[6];
    const int*   src      = (const int*)d_in[7];
    const int*   dst      = (const int*)d_in[8];
    const int*   cat      = (const int*)d_in[9];
    const int*   seeds    = (const int*)d_in[10];
    const int*   cand     = (const int*)d_in[11];
    float* out = (float*)d_out;

    char* wsb = (char*)d_ws;
    float* emb_a = (float*)wsb; wsb += sizeof(float) * (size_t)N_NODES * DIM;
    float* emb_b = (float*)wsb; wsb += sizeof(float) * (size_t)N_NODES * DIM;
    float* cst   = (float*)wsb; wsb += sizeof(float) * (size_t)N_NODES * DIM;
    float* cnew  = (float*)wsb; wsb += sizeof(float) * (size_t)S_SEEDS * DIM;
    float* seedh = (float*)wsb; wsb += sizeof(float) * (size_t)T_STEPS * S_SEEDS * DIM;
    int4* meta   = (int4*)wsb; wsb += sizeof(int4) * (size_t)T_STEPS * NODE_STRIDE;
    int* sorted  = (int*)wsb; wsb += sizeof(int) * (size_t)T_STEPS * E_EDGES;
    int* bh      = (int*)wsb; wsb += sizeof(int) * (size_t)T_STEPS * CBLK * CB;
    int* coffs   = (int*)wsb; wsb += sizeof(int) * T_STEPS * (CB + 1);
    // coarse entry buffer (33.6 MB) aliases emb_b: dead until first fused_agg
    int2* cbuf = (int2*)emb_b;

    // ---- CSR build for all 16 steps (atomic-free two-level sort) ----
    coarse_hist<<<T_STEPS * CBLK, 256, 0, stream>>>(dst, bh);
    scan_bh<<<T_STEPS, 64, 0, stream>>>(bh, coffs);
    coarse_scatter<<<T_STEPS * CBLK, 256, 0, stream>>>(
        src, dst, cat, bh, coffs, cbuf);
    fine_build<<<T_STEPS * CB, 256, 0, stream>>>(cbuf, coffs, meta, sorted);

    hipMemcpyAsync(cst, cx, sizeof(float) * (size_t)N_NODES * DIM,
                   hipMemcpyDeviceToDevice, stream);

    const float* cur = node_emb;     // t=0 reads input table directly
    float* bufs[2] = {emb_b, emb_a};
    const int agg_blocks = (HALFN * D4 + 255) / 256;   // node pairs
    for (int t = 0; t < T_STEPS; t++) {
        float* nxt = bufs[t & 1];
        fused_agg<<<agg_blocks, 256, 0, stream>>>(
            cur, nxt, rel_emb,
            meta + (size_t)t * NODE_STRIDE, sorted + (size_t)t * E_EDGES);
        lstm_kernel<<<S_SEEDS / SPB, 512, 0, stream>>>(
            nxt, cur, cst, seeds + (size_t)t * S_SEEDS,
            W_ih, W_hh, b_ih, b_hh,
            seedh + (size_t)t * S_SEEDS * DIM, cnew);
        scatter_seed<<<(S_SEEDS * D4) / 256, 256, 0, stream>>>(
            nxt, cst, seeds + (size_t)t * S_SEEDS,
            seedh + (size_t)t * S_SEEDS * DIM, cnew);
        cur = nxt;
    }
    score_kernel<<<T_STEPS * S_SEEDS, 64, 0, stream>>>(seedh, cur, cand, out);
}

// Round 12
// 1482.179 us; speedup vs baseline: 1.0267x; 1.0267x over previous
//
#include <hip/hip_runtime.h>
#include <math.h>

#define N_NODES 150000
#define NODE_STRIDE 150016   // padded per-step stride for meta array
#define DIM 100
#define D4 25                // DIM/4 float4 chunks
#define T_STEPS 16
#define E_EDGES 262144
#define S_SEEDS 4096
#define K_CAND 9
#define SPB 16               // seeds per LSTM-role block
#define LSTM_BLOCKS (S_SEEDS / SPB)   // 256 lstm-role blocks, scheduled first

#define CB 64                // coarse buckets per step
#define BSPAN 2344           // nodes per coarse bucket; 64*2344 = 150016 >= N
#define EPT 8                // edges per thread in coarse passes
#define EPB (256 * EPT)      // 2048 edges per coarse block
#define CBLK (E_EDGES / EPB) // 128 coarse blocks per step

__device__ __forceinline__ float sigmoidf_(float x) {
    return 1.0f / (1.0f + __expf(-x));
}

// ============ CSR build: atomic-free two-level counting sort ============

__global__ __launch_bounds__(256) void coarse_hist(
    const int* __restrict__ dst, int* __restrict__ bh) {
    int t = blockIdx.x / CBLK;
    int blk = blockIdx.x % CBLK;
    int base = t * E_EDGES + blk * EPB;
    int tid = threadIdx.x;
    __shared__ int h[CB];
    if (tid < CB) h[tid] = 0;
    __syncthreads();
#pragma unroll
    for (int e = 0; e < EPT; e++) {
        int d = dst[base + e * 256 + tid];
        atomicAdd(&h[d / BSPAN], 1);
    }
    __syncthreads();
    if (tid < CB) bh[(t * CBLK + blk) * CB + tid] = h[tid];
}

__global__ __launch_bounds__(64) void scan_bh(
    int* __restrict__ bh, int* __restrict__ coffs) {
    int t = blockIdx.x;
    int b = threadIdx.x;          // 64 threads = 64 buckets
    int run = 0;
    for (int blk = 0; blk < CBLK; blk++) {
        int idx = (t * CBLK + blk) * CB + b;
        int v = bh[idx];
        bh[idx] = run;
        run += v;
    }
    __shared__ int tot[CB];
    tot[b] = run;
    __syncthreads();
    if (b == 0) {
        int r = 0;
        for (int i = 0; i < CB; i++) { int c = tot[i]; tot[i] = r; r += c; }
    }
    __syncthreads();
    coffs[t * (CB + 1) + b] = tot[b];
    if (b == 0) coffs[t * (CB + 1) + CB] = E_EDGES;
}

__global__ __launch_bounds__(256) void coarse_scatter(
    const int* __restrict__ src, const int* __restrict__ dst,
    const int* __restrict__ cat, const int* __restrict__ bh,
    const int* __restrict__ coffs, int2* __restrict__ cbuf) {
    int t = blockIdx.x / CBLK;
    int blk = blockIdx.x % CBLK;
    int base = t * E_EDGES + blk * EPB;
    int tid = threadIdx.x;
    __shared__ int h[CB];
    __shared__ int gbase[CB];
    if (tid < CB) h[tid] = 0;
    __syncthreads();
    int rank[EPT], bb[EPT], dd[EPT];
#pragma unroll
    for (int e = 0; e < EPT; e++) {
        int d = dst[base + e * 256 + tid];
        int b = d / BSPAN;
        dd[e] = d; bb[e] = b;
        rank[e] = atomicAdd(&h[b], 1);
    }
    __syncthreads();
    if (tid < CB)
        gbase[tid] = coffs[t * (CB + 1) + tid] + bh[(t * CBLK + blk) * CB + tid];
    __syncthreads();
#pragma unroll
    for (int e = 0; e < EPT; e++) {
        int i = base + e * 256 + tid;
        int2 en;
        en.x = src[i] | (cat[i] << 18);
        en.y = dd[e];
        cbuf[(size_t)t * E_EDGES + gbase[bb[e]] + rank[e]] = en;
    }
}

__global__ __launch_bounds__(256) void fine_build(
    const int2* __restrict__ cbuf, const int* __restrict__ coffs,
    int4* __restrict__ meta, int* __restrict__ sorted) {
    int t = blockIdx.x >> 6;
    int b = blockIdx.x & 63;
    int node0 = b * BSPAN;
    int nodes = min(BSPAN, N_NODES - node0);
    int ebeg = coffs[t * (CB + 1) + b];
    int eend = coffs[t * (CB + 1) + b + 1];
    const int2* ebuf = cbuf + (size_t)t * E_EDGES;
    int4* mt = meta + (size_t)t * NODE_STRIDE;
    int* srt = sorted + (size_t)t * E_EDGES;
    __shared__ int cnt[BSPAN];     // counts -> cursor
    __shared__ int begs[BSPAN];    // local exclusive offsets
    __shared__ int sums[256];
    int tid = threadIdx.x;

    for (int j = tid; j < BSPAN; j += 256) cnt[j] = 0;
    __syncthreads();
    for (int e = ebeg + tid; e < eend; e += 256)
        atomicAdd(&cnt[ebuf[e].y - node0], 1);
    __syncthreads();

    const int chunk = (BSPAN + 255) / 256;   // 10
    int cbeg = tid * chunk;
    int cend = min(cbeg + chunk, BSPAN);
    int s = 0;
    for (int j = cbeg; j < cend; j++) s += cnt[j];
    sums[tid] = s;
    __syncthreads();
    for (int d = 1; d < 256; d <<= 1) {
        int v = (tid >= d) ? sums[tid - d] : 0;
        __syncthreads();
        sums[tid] += v;
        __syncthreads();
    }
    int run = (tid == 0) ? 0 : sums[tid - 1];
    for (int j = cbeg; j < cend; j++) {
        int c = cnt[j];
        begs[j] = run;
        cnt[j] = run;                // cursor
        run += c;
    }
    __syncthreads();

    for (int e = ebeg + tid; e < eend; e += 256) {
        int2 en = ebuf[e];
        int pos = atomicAdd(&cnt[en.y - node0], 1);
        srt[ebeg + pos] = en.x;
    }
    __syncthreads();

    for (int j = tid; j < nodes; j += 256) {
        int lbeg = begs[j];
        int deg = cnt[j] - lbeg;
        int gbeg = ebeg + lbeg;
        int4 m;
        m.x = gbeg | (deg << 19);    // gbeg <= 2^18, deg < 2^13
        m.y = (deg > 0) ? srt[gbeg] : 0;
        m.z = (deg > 1) ? srt[gbeg + 1] : 0;
        m.w = (deg > 2) ? srt[gbeg + 2] : 0;
        mt[node0 + j] = m;
    }
}

// ============ Shared per-(node,chunk) aggregation value =====================
// Exactly the measured-best fused_agg math (same FP order) -> bit-identical
// whether stored by agg-role blocks or consumed in-register by lstm role.
__device__ __forceinline__ float4 agg_val(
    const float* __restrict__ emb_in, const float* __restrict__ rel_emb,
    const int4* __restrict__ meta, const int* __restrict__ sorted,
    int node, int q) {
    float4 own = ((const float4*)(emb_in + (size_t)node * DIM))[q];
    int4 m = meta[node];
    int deg = ((unsigned)m.x) >> 19;
    int beg = m.x & 0x7FFFF;
    float4 acc = make_float4(0.f, 0.f, 0.f, 0.f);
    if (deg > 0) {
        float4 mm = ((const float4*)(emb_in + (size_t)(m.y & 0x3FFFF) * DIM))[q];
        float4 rr = ((const float4*)(rel_emb + (size_t)(m.y >> 18) * DIM))[q];
        acc.x += mm.x * rr.x; acc.y += mm.y * rr.y;
        acc.z += mm.z * rr.z; acc.w += mm.w * rr.w;
    }
    if (deg > 1) {
        float4 mm = ((const float4*)(emb_in + (size_t)(m.z & 0x3FFFF) * DIM))[q];
        float4 rr = ((const float4*)(rel_emb + (size_t)(m.z >> 18) * DIM))[q];
        acc.x += mm.x * rr.x; acc.y += mm.y * rr.y;
        acc.z += mm.z * rr.z; acc.w += mm.w * rr.w;
    }
    if (deg > 2) {
        float4 mm = ((const float4*)(emb_in + (size_t)(m.w & 0x3FFFF) * DIM))[q];
        float4 rr = ((const float4*)(rel_emb + (size_t)(m.w >> 18) * DIM))[q];
        acc.x += mm.x * rr.x; acc.y += mm.y * rr.y;
        acc.z += mm.z * rr.z; acc.w += mm.w * rr.w;
    }
    for (int e = beg + 3; e < beg + deg; e++) {
        int p = sorted[e];
        float4 mm = ((const float4*)(emb_in + (size_t)(p & 0x3FFFF) * DIM))[q];
        float4 rr = ((const float4*)(rel_emb + (size_t)(p >> 18) * DIM))[q];
        acc.x += mm.x * rr.x; acc.y += mm.y * rr.y;
        acc.z += mm.z * rr.z; acc.w += mm.w * rr.w;
    }
    float inv = (deg > 0) ? 1.0f / (float)deg : 0.0f;
    own.x += acc.x * inv; own.y += acc.y * inv;
    own.z += acc.z * inv; own.w += acc.w * inv;
    return own;
}

// ============ Fused agg + LSTM (one dispatch, two block roles) ==============
// Blocks [0, LSTM_BLOCKS): LSTM role -- recompute agg for their 16 seeds
// in-register (x), h_prev from cur, gates, activations -> seedh/cnew.
// Blocks [LSTM_BLOCKS, ...): flat agg over all (node, chunk) -> nxt.
// NO cross-role dependency: lstm reads only cur/cst/CSR (never written here);
// agg writes only nxt (never read here). Scatter stays a separate dispatch.
__global__ __launch_bounds__(512, 8) void agg_lstm(
    const float* __restrict__ cur, float* __restrict__ nxt,
    const float* __restrict__ rel_emb, const int4* __restrict__ meta,
    const int* __restrict__ sorted, const float* __restrict__ c_state,
    const int* __restrict__ seeds,
    const float* __restrict__ W_ih, const float* __restrict__ W_hh,
    const float* __restrict__ b_ih, const float* __restrict__ b_hh,
    float* __restrict__ h_out, float* __restrict__ c_out) {
    __shared__ __align__(16) float xs[SPB][DIM];
    __shared__ __align__(16) float hs[SPB][DIM];
    __shared__ __align__(16) float gates[SPB][4 * DIM];
    int tid = threadIdx.x;

    if (blockIdx.x < LSTM_BLOCKS) {
        // ---- LSTM role ----
        int base = blockIdx.x * SPB;
        // stage x = agg(seed) computed in-register; h_prev from cur
        for (int idx = tid; idx < SPB * D4; idx += 512) {
            int s = idx / D4, q = idx - s * D4;
            int node = seeds[base + s];
            ((float4*)xs[s])[q] = agg_val(cur, rel_emb, meta, sorted, node, q);
            ((float4*)hs[s])[q] = ((const float4*)(cur + (size_t)node * DIM))[q];
        }
        __syncthreads();

        if (tid < 4 * DIM) {
            int j = tid;
            float acc[SPB];
#pragma unroll
            for (int s = 0; s < SPB; s++) acc[s] = 0.0f;
            const float4* wi = (const float4*)(W_ih + (size_t)j * DIM);
            const float4* wh = (const float4*)(W_hh + (size_t)j * DIM);
            for (int dc = 0; dc < D4; dc++) {
                float4 a = wi[dc], b = wh[dc];
#pragma unroll
                for (int s = 0; s < SPB; s++) {
                    float4 x = ((const float4*)xs[s])[dc];
                    float4 h = ((const float4*)hs[s])[dc];
                    acc[s] += x.x * a.x + x.y * a.y + x.z * a.z + x.w * a.w
                            + h.x * b.x + h.y * b.y + h.z * b.z + h.w * b.w;
                }
            }
            float bb = b_ih[j] + b_hh[j];
#pragma unroll
            for (int s = 0; s < SPB; s++) gates[s][j] = acc[s] + bb;
        }
        __syncthreads();

        for (int idx = tid; idx < SPB * D4; idx += 512) {
            int s = idx / D4, q = idx - s * D4;
            int node = seeds[base + s];
            float4 ig = ((const float4*)gates[s])[q];
            float4 fg = ((const float4*)(gates[s] + DIM))[q];
            float4 gg = ((const float4*)(gates[s] + 2 * DIM))[q];
            float4 og = ((const float4*)(gates[s] + 3 * DIM))[q];
            float4 cp = ((const float4*)(c_state + (size_t)node * DIM))[q];
            float4 cn, hn;
            cn.x = sigmoidf_(fg.x) * cp.x + sigmoidf_(ig.x) * tanhf(gg.x);
            cn.y = sigmoidf_(fg.y) * cp.y + sigmoidf_(ig.y) * tanhf(gg.y);
            cn.z = sigmoidf_(fg.z) * cp.z + sigmoidf_(ig.z) * tanhf(gg.z);
            cn.w = sigmoidf_(fg.w) * cp.w + sigmoidf_(ig.w) * tanhf(gg.w);
            hn.x = sigmoidf_(og.x) * tanhf(cn.x);
            hn.y = sigmoidf_(og.y) * tanhf(cn.y);
            hn.z = sigmoidf_(og.z) * tanhf(cn.z);
            hn.w = sigmoidf_(og.w) * tanhf(cn.w);
            ((float4*)(h_out + (size_t)(base + s) * DIM))[q] = hn;
            ((float4*)(c_out + (size_t)(base + s) * DIM))[q] = cn;
        }
    } else {
        // ---- agg role: flat over (node, float4-chunk) ----
        unsigned idx = (blockIdx.x - LSTM_BLOCKS) * 512u + tid;
        unsigned node = idx / 25u;
        unsigned q = idx - node * 25u;
        if (node < N_NODES) {
            float4 v = agg_val(cur, rel_emb, meta, sorted, (int)node, (int)q);
            ((float4*)(nxt + (size_t)node * DIM))[q] = v;
        }
    }
}

// duplicate seeds write identical values -> benign
__global__ __launch_bounds__(256) void scatter_seed(
    float* __restrict__ emb, float* __restrict__ c_state,
    const int* __restrict__ seeds,
    const float* __restrict__ h_new, const float* __restrict__ c_new) {
    int i = blockIdx.x * blockDim.x + threadIdx.x;  // over S*D4
    int sd = i / D4, q = i - sd * D4;
    int node = seeds[sd];
    ((float4*)(emb + (size_t)node * DIM))[q] =
        ((const float4*)(h_new + (size_t)sd * DIM))[q];
    ((float4*)(c_state + (size_t)node * DIM))[q] =
        ((const float4*)(c_new + (size_t)sd * DIM))[q];
}

// ============ Scoring (R6 measured-best: ILP, plain loads) ============
__global__ __launch_bounds__(64) void score_kernel(
    const float* __restrict__ seed_h, const float* __restrict__ emb,
    const int* __restrict__ cand_idx, float* __restrict__ out) {
    int n = blockIdx.x;
    int lane = threadIdx.x;
    bool hi = lane + 64 < DIM;
    float u0 = seed_h[(size_t)n * DIM + lane];
    float u1 = hi ? seed_h[(size_t)n * DIM + lane + 64] : 0.0f;
    int cd[K_CAND];
#pragma unroll
    for (int k = 0; k < K_CAND; k++) cd[k] = cand_idx[n * K_CAND + k];
    float p[K_CAND];
#pragma unroll
    for (int k = 0; k < K_CAND; k++) {
        const float* ce = emb + (size_t)cd[k] * DIM;
        p[k] = u0 * ce[lane];
        if (hi) p[k] += u1 * ce[lane + 64];
    }
#pragma unroll
    for (int k = 0; k < K_CAND; k++) {
        for (int off = 32; off > 0; off >>= 1)
            p[k] += __shfl_down(p[k], off);
        if (lane == 0) out[n * K_CAND + k] = p[k];
    }
}

extern "C" void kernel_launch(void* const* d_in, const int* in_sizes, int n_in,
                              void* d_out, int out_size, void* d_ws, size_t ws_size,
                              hipStream_t stream) {
    const float* node_emb = (const float*)d_in[0];
    const float* cx       = (const float*)d_in[1];
    const float* rel_emb  = (const float*)d_in[2];
    const float* W_ih     = (const float*)d_in[3];
    const float* W_hh     = (const float*)d_in[4];
    const float* b_ih     = (const float*)d_in[5];
    const float* b_hh     = (const float*)d_in[6];
    const int*   src      = (const int*)d_in[7];
    const int*   dst      = (const int*)d_in[8];
    const int*   cat      = (const int*)d_in[9];
    const int*   seeds    = (const int*)d_in[10];
    const int*   cand     = (const int*)d_in[11];
    float* out = (float*)d_out;

    char* wsb = (char*)d_ws;
    float* emb_a = (float*)wsb; wsb += sizeof(float) * (size_t)N_NODES * DIM;
    float* emb_b = (float*)wsb; wsb += sizeof(float) * (size_t)N_NODES * DIM;
    float* cst   = (float*)wsb; wsb += sizeof(float) * (size_t)N_NODES * DIM;
    float* cnew  = (float*)wsb; wsb += sizeof(float) * (size_t)S_SEEDS * DIM;
    float* seedh = (float*)wsb; wsb += sizeof(float) * (size_t)T_STEPS * S_SEEDS * DIM;
    int4* meta   = (int4*)wsb; wsb += sizeof(int4) * (size_t)T_STEPS * NODE_STRIDE;
    int* sorted  = (int*)wsb; wsb += sizeof(int) * (size_t)T_STEPS * E_EDGES;
    int* bh      = (int*)wsb; wsb += sizeof(int) * (size_t)T_STEPS * CBLK * CB;
    int* coffs   = (int*)wsb; wsb += sizeof(int) * T_STEPS * (CB + 1);
    // coarse entry buffer (33.6 MB) aliases emb_b: dead until first agg write
    int2* cbuf = (int2*)emb_b;

    // ---- CSR build for all 16 steps (atomic-free two-level sort) ----
    coarse_hist<<<T_STEPS * CBLK, 256, 0, stream>>>(dst, bh);
    scan_bh<<<T_STEPS, 64, 0, stream>>>(bh, coffs);
    coarse_scatter<<<T_STEPS * CBLK, 256, 0, stream>>>(
        src, dst, cat, bh, coffs, cbuf);
    fine_build<<<T_STEPS * CB, 256, 0, stream>>>(cbuf, coffs, meta, sorted);

    hipMemcpyAsync(cst, cx, sizeof(float) * (size_t)N_NODES * DIM,
                   hipMemcpyDeviceToDevice, stream);

    const float* cur = node_emb;     // t=0 reads input table directly
    float* bufs[2] = {emb_b, emb_a};
    const int agg_role_blocks = (N_NODES * D4 + 511) / 512;   // 7325
    for (int t = 0; t < T_STEPS; t++) {
        float* nxt = bufs[t & 1];
        agg_lstm<<<LSTM_BLOCKS + agg_role_blocks, 512, 0, stream>>>(
            cur, nxt, rel_emb,
            meta + (size_t)t * NODE_STRIDE, sorted + (size_t)t * E_EDGES,
            cst, seeds + (size_t)t * S_SEEDS,
            W_ih, W_hh, b_ih, b_hh,
            seedh + (size_t)t * S_SEEDS * DIM, cnew);
        scatter_seed<<<(S_SEEDS * D4) / 256, 256, 0, stream>>>(
            nxt, cst, seeds + (size_t)t * S_SEEDS,
            seedh + (size_t)t * S_SEEDS * DIM, cnew);
        cur = nxt;
    }
    score_kernel<<<T_STEPS * S_SEEDS, 64, 0, stream>>>(seedh, cur, cand, out);
}